// Round 1
// baseline (495.875 us; speedup 1.0000x reference)
//
#include <hip/hip_runtime.h>
#include <hip/hip_bf16.h>

// Problem: B=32, S=2048, ENC=1024, DEC=512
//   h_proj[b,e]   = sum_d hidden[b,d] * W[e,d]            (Wh = W[:, :512])
//   e_proj[b,s,d] = sum_e enc[b,s,e] * W[d, 512+e]        (We = W[:, 512:])
//   energy = tanh(e_proj + h_proj + bias); scores = v . energy; attn = softmax_s

typedef __attribute__((ext_vector_type(8))) short bf16x8;
typedef __attribute__((ext_vector_type(4))) float f32x4;

__device__ __forceinline__ ushort f2bf(float x) {
    __hip_bfloat16 h = __float2bfloat16(x);
    return *reinterpret_cast<ushort*>(&h);
}

// ws layout (bytes):
//   [0, 1MB)            : Wbf  bf16 [512][1024]  (We transposed-stationary: row n=d, col k=e)
//   [1MB, 1MB+64KB)     : hb   f32  [32][512]    (h_proj + bias)
//   [1MB+64KB, +256KB)  : scores f32 [32][2048]
#define WS_WBF   0
#define WS_HB    (1u << 20)
#define WS_SCORE ((1u << 20) + (64u << 10))

// ---- We -> bf16, layout [d][e] (row-major, k contiguous == B^T for the GEMM) ----
__global__ void convert_we(const float* __restrict__ W, ushort* __restrict__ Wbf) {
    int idx = blockIdx.x * 256 + threadIdx.x;   // 131072 threads, 4 elems each
    int d  = idx >> 8;
    int e4 = (idx & 255) * 4;
    float4 f = *(const float4*)(W + (size_t)d * 1536 + 512 + e4);
    ushort4 u;
    u.x = f2bf(f.x); u.y = f2bf(f.y); u.z = f2bf(f.z); u.w = f2bf(f.w);
    *(ushort4*)(Wbf + (size_t)d * 1024 + e4) = u;
}

// ---- hb[b][d] = sum_j hidden[b][j] * W[d][j] + bias[d]  (exact fp32) ----
__global__ void hproj_kernel(const float* __restrict__ hidden,
                             const float* __restrict__ W,
                             const float* __restrict__ bias,
                             float* __restrict__ hb) {
    int idx = blockIdx.x * 256 + threadIdx.x;   // 16384 = 32*512
    int b = idx >> 9, d = idx & 511;
    const float4* hp = (const float4*)(hidden + b * 512);
    const float4* wp = (const float4*)(W + (size_t)d * 1536);
    float acc = 0.f;
#pragma unroll 8
    for (int j = 0; j < 128; ++j) {
        float4 h = hp[j], w = wp[j];
        acc += h.x * w.x + h.y * w.y + h.z * w.z + h.w * w.w;
    }
    hb[idx] = acc + bias[d];
}

// ---- main: e_proj GEMM (M=65536,N=512,K=1024) fused with tanh + v-dot -> scores ----
// block = 256 thr (4 waves); block owns 64 M-rows x all 512 N-cols; wave w owns cols [w*128, w*128+128)
// A (encoder, fp32) staged->bf16 in LDS; B (Wbf) streamed from L2 into frag regs.
__launch_bounds__(256, 2)
__global__ void eproj_scores(const float* __restrict__ enc,
                             const ushort* __restrict__ Wbf,
                             const float* __restrict__ hb,
                             const float* __restrict__ v,
                             float* __restrict__ scores) {
    __shared__ ushort Alds[64 * 72];      // 64 rows x 64 k, stride 72 (pad 8) bf16
    __shared__ float  spart[4][64];

    const int tid = threadIdx.x;
    const int l  = tid & 63, w = tid >> 6;
    const int q  = l >> 4,  ln = l & 15;
    const long m0 = (long)blockIdx.x * 64;
    const int  nbase = w * 128;

    f32x4 acc[4][8];
#pragma unroll
    for (int mt = 0; mt < 4; ++mt)
#pragma unroll
        for (int nt = 0; nt < 8; ++nt)
            acc[mt][nt] = (f32x4){0.f, 0.f, 0.f, 0.f};

    for (int kt = 0; kt < 1024; kt += 64) {
        __syncthreads();
        // stage A-tile: 64 rows x 64 cols fp32 -> bf16 LDS (each thread: 4 x float4)
#pragma unroll
        for (int i = 0; i < 4; ++i) {
            int idx = tid + 256 * i;
            int row = idx >> 4, ch = idx & 15;
            float4 f = *(const float4*)(enc + (m0 + row) * 1024 + kt + ch * 4);
            ushort4 u;
            u.x = f2bf(f.x); u.y = f2bf(f.y); u.z = f2bf(f.z); u.w = f2bf(f.w);
            *(ushort4*)(&Alds[row * 72 + ch * 4]) = u;
        }
        __syncthreads();
#pragma unroll
        for (int ks = 0; ks < 64; ks += 32) {
            bf16x8 af[4];
#pragma unroll
            for (int mt = 0; mt < 4; ++mt)
                af[mt] = *(bf16x8*)(&Alds[(ln + 16 * mt) * 72 + ks + q * 8]);
#pragma unroll
            for (int nt = 0; nt < 8; ++nt) {
                int n = nbase + nt * 16 + ln;
                bf16x8 bfr = *(const bf16x8*)(Wbf + (size_t)n * 1024 + kt + ks + q * 8);
#pragma unroll
                for (int mt = 0; mt < 4; ++mt)
                    acc[mt][nt] = __builtin_amdgcn_mfma_f32_16x16x32_bf16(
                        af[mt], bfr, acc[mt][nt], 0, 0, 0);
            }
        }
    }

    // epilogue: energy = tanh(acc + hb), partial = sum_d v[d]*energy
    const int bidx = (int)(m0 >> 11);     // m0 / 2048
    float partial[4][4];
#pragma unroll
    for (int mt = 0; mt < 4; ++mt)
#pragma unroll
        for (int r = 0; r < 4; ++r) partial[mt][r] = 0.f;

#pragma unroll
    for (int nt = 0; nt < 8; ++nt) {
        int d = nbase + nt * 16 + ln;
        float hbv = hb[bidx * 512 + d];
        float vv  = v[d];
#pragma unroll
        for (int mt = 0; mt < 4; ++mt)
#pragma unroll
            for (int r = 0; r < 4; ++r) {
                float x = acc[mt][nt][r] + hbv;
                float e = __expf(2.f * x);          // tanh(x) = 1 - 2/(e^{2x}+1)
                partial[mt][r] += vv * (1.f - 2.f / (e + 1.f));
            }
    }
    // reduce over the 16 lanes sharing q (xor masks stay inside the 16-lane group)
#pragma unroll
    for (int mt = 0; mt < 4; ++mt)
#pragma unroll
        for (int r = 0; r < 4; ++r) {
            float s = partial[mt][r];
            s += __shfl_xor(s, 1);
            s += __shfl_xor(s, 2);
            s += __shfl_xor(s, 4);
            s += __shfl_xor(s, 8);
            partial[mt][r] = s;
        }
    if (ln == 0) {
#pragma unroll
        for (int mt = 0; mt < 4; ++mt)
#pragma unroll
            for (int r = 0; r < 4; ++r)
                spart[w][mt * 16 + q * 4 + r] = partial[mt][r];
    }
    __syncthreads();
    if (tid < 64) {
        float s = spart[0][tid] + spart[1][tid] + spart[2][tid] + spart[3][tid];
        scores[m0 + tid] = s;
    }
}

// ---- softmax over S=2048 per b ----
__global__ void softmax_kernel(const float* __restrict__ scores, float* __restrict__ out) {
    int b = blockIdx.x;
    const float* sc = scores + b * 2048;
    __shared__ float wred[4], wsum[4];

    float lmax = -1e30f;
    for (int i = threadIdx.x; i < 2048; i += 256) lmax = fmaxf(lmax, sc[i]);
#pragma unroll
    for (int m = 1; m < 64; m <<= 1) lmax = fmaxf(lmax, __shfl_xor(lmax, m));
    if ((threadIdx.x & 63) == 0) wred[threadIdx.x >> 6] = lmax;
    __syncthreads();
    float gmax = fmaxf(fmaxf(wred[0], wred[1]), fmaxf(wred[2], wred[3]));

    float lsum = 0.f;
    for (int i = threadIdx.x; i < 2048; i += 256) lsum += __expf(sc[i] - gmax);
#pragma unroll
    for (int m = 1; m < 64; m <<= 1) lsum += __shfl_xor(lsum, m);
    if ((threadIdx.x & 63) == 0) wsum[threadIdx.x >> 6] = lsum;
    __syncthreads();
    float inv = 1.f / (wsum[0] + wsum[1] + wsum[2] + wsum[3]);

    for (int i = threadIdx.x; i < 2048; i += 256)
        out[b * 2048 + i] = __expf(sc[i] - gmax) * inv;
}

extern "C" void kernel_launch(void* const* d_in, const int* in_sizes, int n_in,
                              void* d_out, int out_size, void* d_ws, size_t ws_size,
                              hipStream_t stream) {
    const float* hidden = (const float*)d_in[0];   // 32 x 512
    const float* enc    = (const float*)d_in[1];   // 32 x 2048 x 1024
    const float* W      = (const float*)d_in[2];   // 512 x 1536
    const float* bias   = (const float*)d_in[3];   // 512
    const float* v      = (const float*)d_in[4];   // 512
    float* out = (float*)d_out;                    // 32 x 1 x 2048

    char* ws = (char*)d_ws;
    ushort* Wbf   = (ushort*)(ws + WS_WBF);
    float*  hb    = (float*)(ws + WS_HB);
    float*  score = (float*)(ws + WS_SCORE);

    hipLaunchKernelGGL(convert_we,   dim3(512),  dim3(256), 0, stream, W, Wbf);
    hipLaunchKernelGGL(hproj_kernel, dim3(64),   dim3(256), 0, stream, hidden, W, bias, hb);
    hipLaunchKernelGGL(eproj_scores, dim3(1024), dim3(256), 0, stream, enc, Wbf, hb, v, score);
    hipLaunchKernelGGL(softmax_kernel, dim3(32), dim3(256), 0, stream, score, out);
}